// Round 6
// baseline (321.717 us; speedup 1.0000x reference)
//
#include <hip/hip_runtime.h>

typedef int v4i  __attribute__((ext_vector_type(4)));
typedef int v16i __attribute__((ext_vector_type(16)));

__device__ __forceinline__ int pack4i(int a, int b, int c, int d) {
  return (a & 255) | ((b & 255) << 8) | ((c & 255) << 16) | ((d & 255) << 24);
}
// SWAR per-byte add (mod-256 per lane-byte)
__device__ __forceinline__ int badd4(int a, int b) {
  return ((a & 0x7f7f7f7f) + (b & 0x7f7f7f7f)) ^ ((a ^ b) & 0x80808080);
}

// ---------------------------------------------------------------------------
// Pack (W + E) -> int8, transposed Bt[n][k] (row stride K bytes).
// Tile: 64 n x 256 k per block, 256 threads. Zero-pads n >= N rows.
// ---------------------------------------------------------------------------
__device__ void pack_tile(const int* __restrict__ W, const int* __restrict__ E,
                          char* __restrict__ Bt, int K, int N,
                          int nx, int ky, char* lin) {
  const int t = threadIdx.x;
  const int n0 = nx * 64, k0 = ky * 256;
  {
    const int kk = t >> 2, c = t & 3;
    for (int p = 0; p < 4; ++p) {
      const int k = kk + (p << 6);
      const long grow = (long)(k0 + k) * N;
      #pragma unroll
      for (int i = 0; i < 4; ++i) {
        const int nl = (c << 4) + (i << 2);
        const int ng = n0 + nl;
        int a0, a1, a2, a3;
        if (ng + 3 < N) {
          int4 wv = *(const int4*)(W + grow + ng);
          int4 ev = *(const int4*)(E + grow + ng);
          a0 = wv.x + ev.x; a1 = wv.y + ev.y; a2 = wv.z + ev.z; a3 = wv.w + ev.w;
        } else {
          a0 = (ng + 0 < N) ? W[grow + ng + 0] + E[grow + ng + 0] : 0;
          a1 = (ng + 1 < N) ? W[grow + ng + 1] + E[grow + ng + 1] : 0;
          a2 = (ng + 2 < N) ? W[grow + ng + 2] + E[grow + ng + 2] : 0;
          a3 = (ng + 3 < N) ? W[grow + ng + 3] + E[grow + ng + 3] : 0;
        }
        *(int*)(lin + k * 68 + nl) = pack4i(a0, a1, a2, a3);
      }
    }
  }
  __syncthreads();
  {
    const int n = t & 63, kq = t >> 6;
    char* dst = Bt + (long)(n0 + n) * K + k0 + (kq << 6);
    int outv[16];
    #pragma unroll
    for (int g = 0; g < 16; ++g) {
      const int k = (kq << 6) + (g << 2);
      outv[g] = pack4i(lin[(k + 0) * 68 + n], lin[(k + 1) * 68 + n],
                       lin[(k + 2) * 68 + n], lin[(k + 3) * 68 + n]);
    }
    #pragma unroll
    for (int g = 0; g < 4; ++g)
      *(int4*)(dst + (g << 4)) =
          make_int4(outv[g * 4], outv[g * 4 + 1], outv[g * 4 + 2], outv[g * 4 + 3]);
  }
}

// int32 -> int8 copy with G independent 64B load groups in flight per thread.
template<int G>
__device__ void pack_ilp(const int* __restrict__ src, char* __restrict__ dst,
                         long base, int supers) {
  const int t = threadIdx.x;
  for (int s = 0; s < supers; ++s) {
    int4 v[G][4];
    #pragma unroll
    for (int g = 0; g < G; ++g) {
      const long i0 = base + ((long)(t + (s * G + g) * 256) << 4);
      const int* p = src + i0;
      v[g][0] = ((const int4*)p)[0];
      v[g][1] = ((const int4*)p)[1];
      v[g][2] = ((const int4*)p)[2];
      v[g][3] = ((const int4*)p)[3];
    }
    #pragma unroll
    for (int g = 0; g < G; ++g) {
      const long i0 = base + ((long)(t + (s * G + g) * 256) << 4);
      *(int4*)(dst + i0) = make_int4(
          pack4i(v[g][0].x, v[g][0].y, v[g][0].z, v[g][0].w),
          pack4i(v[g][1].x, v[g][1].y, v[g][1].z, v[g][1].w),
          pack4i(v[g][2].x, v[g][2].y, v[g][2].z, v[g][2].w),
          pack4i(v[g][3].x, v[g][3].y, v[g][3].z, v[g][3].w));
    }
  }
}

// ---------------------------------------------------------------------------
// pack_all: weight tiles + biases + X->X8 + H->H8 (into d_out scratch region).
// ---------------------------------------------------------------------------
__global__ __launch_bounds__(256) void pack_all_kernel(
    const int* W1, const int* E1, char* Bt1,
    const int* W2, const int* E2, char* Bt2,
    const int* W3, const int* E3, char* Bt3,
    const int* b1, const int* eb1, int* bs1,
    const int* b2, const int* eb2, int* bs2,
    const int* b3, const int* eb3, int* bs3,
    const int* X, char* X8, const int* H, char* H8) {
  __shared__ __align__(16) char lin[256 * 68];
  const int bid = blockIdx.x;
  if (bid < 192) {
    pack_tile(W1, E1, Bt1, 3072, 1024, bid % 16, bid / 16, lin);
  } else if (bid < 256) {
    const int l = bid - 192;
    pack_tile(W2, E2, Bt2, 1024, 1024, l % 16, l / 16, lin);
  } else if (bid < 264) {
    const int l = bid - 256;
    pack_tile(W3, E3, Bt3, 1024, 100, l & 1, l >> 1, lin);
  } else if (bid == 264) {
    const int t = threadIdx.x;
    for (int i = t; i < 1024; i += 256) {
      bs1[i] = b1[i] + eb1[i];
      bs2[i] = b2[i] + eb2[i];
    }
    for (int i = t; i < 128; i += 256)
      bs3[i] = (i < 100) ? (b3[i] + eb3[i]) : 0;
  } else if (bid < 1289) {
    // X: 25,165,824 ints; 1024 blocks x 24576 ints (2 supers x 3 groups)
    pack_ilp<3>(X, X8, (long)(bid - 265) * 24576, 2);
  } else {
    // H: 8,388,608 ints; 256 blocks x 32768 ints (2 supers x 4 groups)
    pack_ilp<4>(H, H8, (long)(bid - 1289) * 32768, 2);
  }
}

// ---------------------------------------------------------------------------
// GEMM: 64x128 tile, BK=64, 256 thr (4 waves, each 64x32), 3-deep pipeline:
// 2 register prefetch sets + 2-stage LDS. A tile's global loads stay in
// flight for 2 K-iters before the LDS store consumes them (vmcnt(N) style).
// Grid 1024 -> 4 blocks/CU. mt = bid&127 so the 8 blocks sharing an A-tile
// are congruent mod 8 -> same XCD L2.
// EPI 0: A8out = trunc8(acc+bs) SWAR+ H8, int8, via LDS transpose  (layer 1)
// EPI 1: Iout  = trunc8(acc+bs) as int32, direct                   (layer 2)
// ---------------------------------------------------------------------------
template<int EPI>
__global__ __launch_bounds__(256, 4) void gemm_kernel(
    const char* __restrict__ A, const char* __restrict__ Btg,
    const int* __restrict__ bsum, const char* __restrict__ H8,
    char* __restrict__ A8out, int* __restrict__ Iout, const int K) {
  // stage: As [64][80] (5120) + Bs [128][80] (10240) = 15360; x2 = 30720
  __shared__ __align__(16) char smem[30720];

  const int t = threadIdx.x;
  const int bid = blockIdx.x;
  const int mt = bid & 127, nt = bid >> 7;
  const long m0 = (long)mt << 6;
  const int n0 = nt << 7;

  const int lane = t & 63, w = t >> 6;
  const int lc = lane & 31, hg = lane >> 5;

  v16i acc[2] = {};

  // A staging: 64 rows x 4 thr x 16B ; B staging: 128 rows x 2 thr x 32B
  const int am = t >> 2, ah = t & 3;
  const char* Arow = A + (m0 + am) * (long)K + ah * 16;
  const int aoff = am * 80 + ah * 16;
  const int bm = t >> 1, bh = t & 1;
  const char* Brow = Btg + (long)(n0 + bm) * K + bh * 32;
  const int boff = bm * 80 + bh * 32;

  const int abo = lc * 80 + hg * 16;
  const int bbo = (w * 32 + lc) * 80 + hg * 16;

  int4 a0r, b0r0, b0r1;   // prefetch set 0
  int4 a1r, b1r0, b1r1;   // prefetch set 1

  auto LOAD = [&](int kb, int4& a, int4& b0, int4& b1) {
    a  = *(const int4*)(Arow + kb);
    b0 = *(const int4*)(Brow + kb);
    b1 = *(const int4*)(Brow + kb + 16);
  };
  auto STORE = [&](int stage, const int4& a, const int4& b0, const int4& b1) {
    char* base = smem + stage * 15360;
    *(int4*)(base + aoff) = a;
    *(int4*)(base + 5120 + boff)      = b0;
    *(int4*)(base + 5120 + boff + 16) = b1;
  };
  auto MFMA = [&](int stage) {
    const char* base = smem + stage * 15360;
    const char* Ab = base + abo;
    const char* Bb = base + 5120 + bbo;
    #pragma unroll
    for (int ks = 0; ks < 2; ++ks) {
      v4i a0 = *(const v4i*)(Ab + ks * 32);
      v4i a1 = *(const v4i*)(Ab + 32 * 80 + ks * 32);
      v4i b  = *(const v4i*)(Bb + ks * 32);
      acc[0] = __builtin_amdgcn_mfma_i32_32x32x32_i8(a0, b, acc[0], 0, 0, 0);
      acc[1] = __builtin_amdgcn_mfma_i32_32x32x32_i8(a1, b, acc[1], 0, 0, 0);
    }
  };

  const int kiters = K >> 6;   // 48 or 16, even
  LOAD(0, a0r, b0r0, b0r1);
  STORE(0, a0r, b0r0, b0r1);
  LOAD(64, a1r, b1r0, b1r1);
  __syncthreads();

  for (int kt = 0; kt < kiters; kt += 2) {
    // even half: compute buf0 (tile kt); set1 holds tile kt+1
    MFMA(0);
    if (kt + 2 < kiters) LOAD((kt + 2) << 6, a0r, b0r0, b0r1);
    STORE(1, a1r, b1r0, b1r1);
    __syncthreads();
    // odd half: compute buf1 (tile kt+1); set0 holds tile kt+2
    MFMA(1);
    if (kt + 3 < kiters) LOAD((kt + 3) << 6, a1r, b1r0, b1r1);
    if (kt + 2 < kiters) {
      STORE(0, a0r, b0r0, b0r1);
      __syncthreads();
    }
  }

  // Epilogue. C/D layout: col = lane&31, row = (reg&3) + 8*(reg>>2) + 4*hg.
  const int gcl = w * 32 + lc;
  const int bs = bsum[n0 + gcl];
  if (EPI == 1) {
    #pragma unroll
    for (int tm = 0; tm < 2; ++tm) {
      #pragma unroll
      for (int r = 0; r < 16; ++r) {
        const int row = tm * 32 + (hg << 2) + (r & 3) + ((r >> 2) << 3);
        Iout[(m0 + row) * 1024 + n0 + gcl] = (int)(signed char)(acc[tm][r] + bs);
      }
    }
  } else {
    __syncthreads();   // smem reused as 64x144 transpose buffer
    #pragma unroll
    for (int tm = 0; tm < 2; ++tm) {
      #pragma unroll
      for (int r = 0; r < 16; ++r) {
        const int row = tm * 32 + (hg << 2) + (r & 3) + ((r >> 2) << 3);
        smem[row * 144 + gcl] = (char)(acc[tm][r] + bs);
      }
    }
    __syncthreads();
    // readout: thread -> row t>>2, 32 bytes at (t&3)*32 ; SWAR-add H8
    const char* src = smem + (t >> 2) * 144 + (t & 3) * 32;
    const long gm = m0 + (t >> 2);
    const long gco = gm * 1024 + n0 + (t & 3) * 32;
    int4 s0 = *(const int4*)(src);
    int4 s1 = *(const int4*)(src + 16);
    int4 h0 = *(const int4*)(H8 + gco);
    int4 h1 = *(const int4*)(H8 + gco + 16);
    s0 = make_int4(badd4(s0.x, h0.x), badd4(s0.y, h0.y),
                   badd4(s0.z, h0.z), badd4(s0.w, h0.w));
    s1 = make_int4(badd4(s1.x, h1.x), badd4(s1.y, h1.y),
                   badd4(s1.z, h1.z), badd4(s1.w, h1.w));
    *(int4*)(A8out + gco)      = s0;
    *(int4*)(A8out + gco + 16) = s1;
  }
}

// ---------------------------------------------------------------------------
// Layer 3: 32x128 tile (256 blocks), K=1024, A = h2 int32 from d_out.
// Same 3-deep pipeline.
// ---------------------------------------------------------------------------
__global__ __launch_bounds__(256, 2) void gemm3_kernel(
    const int* __restrict__ h2, const char* __restrict__ Btg,
    const int* __restrict__ bsum, int* __restrict__ Iout) {
  __shared__ __align__(16) char smem[25600];
  const int t = threadIdx.x;
  const int m0 = blockIdx.x << 5;
  const int lane = t & 63, w = t >> 6;
  const int lc = lane & 31, hg = lane >> 5;
  v16i acc = {};

  const int am = t >> 3, ah = t & 7;
  const long arow = (long)(m0 + am) * 1024 + ah * 8;
  const int aoff = am * 80 + ah * 8;
  const int bm = t >> 1, bh = t & 1;
  const char* Brow = Btg + (long)bm * 1024 + bh * 32;
  const int boff = bm * 80 + bh * 32;

  int4 a0r0, a0r1, b0r0, b0r1;   // set 0
  int4 a1r0, a1r1, b1r0, b1r1;   // set 1

  auto LOAD = [&](int kb, int4& a0, int4& a1, int4& b0, int4& b1) {
    const int* Ar = h2 + arow + kb;
    a0 = *(const int4*)(Ar);
    a1 = *(const int4*)(Ar + 4);
    b0 = *(const int4*)(Brow + kb);
    b1 = *(const int4*)(Brow + kb + 16);
  };
  auto STORE = [&](int stage, const int4& a0, const int4& a1,
                   const int4& b0, const int4& b1) {
    char* As_ = smem + stage * 12800;
    char* Bs_ = As_ + 2560;
    int2 d;
    d.x = pack4i(a0.x, a0.y, a0.z, a0.w);
    d.y = pack4i(a1.x, a1.y, a1.z, a1.w);
    *(int2*)(As_ + aoff) = d;
    *(int4*)(Bs_ + boff)      = b0;
    *(int4*)(Bs_ + boff + 16) = b1;
  };
  auto MFMA = [&](int stage) {
    const char* base = smem + stage * 12800;
    const char* Ab = base + lc * 80 + hg * 16;
    const char* Bb = base + 2560 + (w * 32 + lc) * 80 + hg * 16;
    #pragma unroll
    for (int ks = 0; ks < 2; ++ks) {
      v4i a = *(const v4i*)(Ab + ks * 32);
      v4i b = *(const v4i*)(Bb + ks * 32);
      acc = __builtin_amdgcn_mfma_i32_32x32x32_i8(a, b, acc, 0, 0, 0);
    }
  };

  LOAD(0, a0r0, a0r1, b0r0, b0r1);
  STORE(0, a0r0, a0r1, b0r0, b0r1);
  LOAD(64, a1r0, a1r1, b1r0, b1r1);
  __syncthreads();

  for (int kt = 0; kt < 16; kt += 2) {
    MFMA(0);
    if (kt + 2 < 16) LOAD((kt + 2) << 6, a0r0, a0r1, b0r0, b0r1);
    STORE(1, a1r0, a1r1, b1r0, b1r1);
    __syncthreads();
    MFMA(1);
    if (kt + 3 < 16) LOAD((kt + 3) << 6, a1r0, a1r1, b1r0, b1r1);
    if (kt + 2 < 16) {
      STORE(0, a0r0, a0r1, b0r0, b0r1);
      __syncthreads();
    }
  }

  const int gcl = w * 32 + lc;
  if (gcl < 100) {
    const int bs = bsum[gcl];
    #pragma unroll
    for (int r = 0; r < 16; ++r) {
      const int row = (r & 3) + ((r >> 2) << 3) + (hg << 2);
      Iout[(long)(m0 + row) * 100 + gcl] = (int)(signed char)(acc[r] + bs);
    }
  }
}

// ---------------------------------------------------------------------------
// ws (12.7 MB): Bt1 | Bt2 | Bt3 | bs1 | bs2 | bs3 | A2
// d_out scratch: X8 [0,25.2M) + H8 [25.2M,33.6M) — both dead before L2
// overwrites the region with h2 (launch order on one stream guarantees it).
// ---------------------------------------------------------------------------
extern "C" void kernel_launch(void* const* d_in, const int* in_sizes, int n_in,
                              void* d_out, int out_size, void* d_ws, size_t ws_size,
                              hipStream_t stream) {
  (void)in_sizes; (void)n_in; (void)out_size; (void)ws_size;
  const int* W1  = (const int*)d_in[0];
  const int* b1  = (const int*)d_in[1];
  const int* W2  = (const int*)d_in[2];
  const int* b2  = (const int*)d_in[3];
  const int* W3  = (const int*)d_in[4];
  const int* b3  = (const int*)d_in[5];
  const int* E1  = (const int*)d_in[6];
  const int* eb1 = (const int*)d_in[7];
  const int* E2  = (const int*)d_in[8];
  const int* eb2 = (const int*)d_in[9];
  const int* E3  = (const int*)d_in[10];
  const int* eb3 = (const int*)d_in[11];
  const int* X   = (const int*)d_in[12];   // [8192][3072] int32
  const int* H   = (const int*)d_in[13];   // [8192][1024] int32
  int* out = (int*)d_out;                  // h2 [8192*1024] then out [8192*100]

  char* ws  = (char*)d_ws;
  char* Bt1 = ws;                          // 3,145,728
  char* Bt2 = Bt1 + 3145728;               // 1,048,576
  char* Bt3 = Bt2 + 1048576;               //   131,072 (rows 100..127 zeroed)
  int*  bs1 = (int*)(Bt3 + 131072);        // 1024 ints
  int*  bs2 = bs1 + 1024;                  // 1024 ints
  int*  bs3 = bs2 + 1024;                  //  128 ints
  char* A2  = (char*)(bs3 + 128);          // 8,388,608 int8
  char* X8  = (char*)d_out;                // 25,165,824 int8 (temp in d_out)
  char* H8  = X8 + 25165824;               //  8,388,608 int8 (temp in d_out)

  pack_all_kernel<<<dim3(1545), dim3(256), 0, stream>>>(
      W1, E1, Bt1, W2, E2, Bt2, W3, E3, Bt3,
      b1, eb1, bs1, b2, eb2, bs2, b3, eb3, bs3, X, X8, H, H8);

  // Layer 1: i2c + hiddens-add -> A2 (int8)
  gemm_kernel<0><<<dim3(1024), dim3(256), 0, stream>>>(
      X8, Bt1, bs1, H8, A2, nullptr, 3072);

  // Layer 2: h2 -> d_out (int32)
  gemm_kernel<1><<<dim3(1024), dim3(256), 0, stream>>>(
      A2, Bt2, bs2, nullptr, nullptr, out, 1024);

  // Layer 3: reads h2 from d_out (int32), writes out region (int32)
  gemm3_kernel<<<dim3(256), dim3(256), 0, stream>>>(
      out, Bt3, bs3, out + 8388608);
}